// Round 15
// baseline (126.807 us; speedup 1.0000x reference)
//
#include <hip/hip_runtime.h>
#include <cstdint>

#define NPIX 3136
#define HGT 56
#define WID 56
#define NPAD 3200   // padded pixel count for BM=128 tiling

typedef __bf16 bf16x8 __attribute__((ext_vector_type(8)));
typedef __bf16 bf16x4 __attribute__((ext_vector_type(4)));
typedef __bf16 bf16x2 __attribute__((ext_vector_type(2)));
typedef float  f32x4  __attribute__((ext_vector_type(4)));
typedef float  f32x2  __attribute__((ext_vector_type(2)));

typedef const __attribute__((address_space(1))) unsigned int* gptr_t;
typedef __attribute__((address_space(3))) unsigned int* lptr_t;

__device__ __forceinline__ void gload_lds16(const __bf16* g, __bf16* l) {
    __builtin_amdgcn_global_load_lds((gptr_t)(const void*)g, (lptr_t)(void*)l, 16, 0, 0);
}

// tanh-form GELU, |err vs exact gelu| < ~3e-3 (threshold is 4.9e-2)
__device__ __forceinline__ float fast_gelu(float x) {
    float y = 0.7978845608f * x * (1.f + 0.044715f * x * x);
    float t = __expf(-2.f * fabsf(y));
    float th = (1.f - t) * __builtin_amdgcn_rcpf(1.f + t);
    th = copysignf(th, y);
    return 0.5f * x * (1.f + th);
}

// ---------------------------------------------------------------------------
// Convert both weight matrices to bf16 (row-major, k contiguous).
// ---------------------------------------------------------------------------
__global__ __launch_bounds__(256) void wcvt(
    const float* __restrict__ wq, const float* __restrict__ wp,
    __bf16* __restrict__ oq, __bf16* __restrict__ op)
{
    int i = blockIdx.x * 256 + threadIdx.x;
    if (i < 768 * 256) oq[i] = (__bf16)wq[i];
    if (i < 256 * 512) op[i] = (__bf16)wp[i];
}

// ---------------------------------------------------------------------------
// x [8][256][3136] f32 -> xT [8][3200][256] bf16 (n-major), zero-padded rows.
// ---------------------------------------------------------------------------
__global__ __launch_bounds__(256) void xpose_cvt(
    const float* __restrict__ x, __bf16* __restrict__ xT)
{
    __shared__ float t[32][33];
    const int n0 = blockIdx.x * 32;
    const int k0 = blockIdx.y * 32;
    const int b  = blockIdx.z;
    const int tid = threadIdx.x;
    const int ln = tid & 31, lk = tid >> 5;
    #pragma unroll
    for (int r = 0; r < 4; ++r) {
        int n = n0 + ln, k = k0 + lk + r * 8;
        t[lk + r * 8][ln] = (n < NPIX) ? x[((size_t)b * 256 + k) * NPIX + n] : 0.f;
    }
    __syncthreads();
    const int nr = tid >> 3, kc = (tid & 7) * 4;
    bf16x4 o;
    #pragma unroll
    for (int i = 0; i < 4; ++i) o[i] = (__bf16)t[kc + i][nr];
    *(bf16x4*)&xT[((size_t)b * NPAD + n0 + nr) * 256 + k0 + kc] = o;
}

// ---------------------------------------------------------------------------
// bf16 MFMA GEMM: C[b][m][n] = sum_k A[m][k] * B[b][n][k]
// BM=128, BK=32, 4 waves. MODE 0: bf16 planar out.  MODE 1: f32 + BN.
// Flat 1-D grid, XCD-co-location decode.
// ---------------------------------------------------------------------------
template<int BN, int MODE>
__global__ __launch_bounds__(256) void gemm1x1(
    const __bf16* __restrict__ A,   // [M][K]
    const __bf16* __restrict__ Bm,  // [batch][NP][K]
    void* __restrict__ Cout,
    const int M, const int K, const int N, const int NP,
    const int NT, const int MT,
    const float* __restrict__ bn_g, const float* __restrict__ bn_b,
    const float* __restrict__ bn_m, const float* __restrict__ bn_v)
{
    constexpr int NFRAG = BN / 32;
    __shared__ __bf16 As[128 * 32];
    __shared__ __bf16 Bs[BN * 32];
    const int tid = threadIdx.x;

    // XCD-co-location decode
    const int F = blockIdx.x;
    const int gpb = MT * 8;
    const int A_ = F / gpb, R_ = F % gpb;
    const int mi = R_ >> 3, ci = R_ & 7;
    const int g_ = A_ * 8 + ci;
    const int n0 = (g_ % NT) * BN;
    const int b  = g_ / NT;
    const int m0 = mi * 128;

    const int lane = tid & 63, wid = tid >> 6;
    const int wr = wid >> 1, wc = wid & 1;
    const int lr = lane & 15, lk = (lane >> 4) * 8;

    f32x4 acc[4][NFRAG] = {};
    const __bf16* Ap = A + (size_t)m0 * K;
    const __bf16* Bp = Bm + ((size_t)b * NP + n0) * K;
    const int ar = tid >> 2, ac = (tid & 3) * 8;

    for (int k0 = 0; k0 < K; k0 += 32) {
        __syncthreads();
        gload_lds16(Ap + (size_t)ar * K + k0 + ac,          As + ar * 32 + ac);
        gload_lds16(Ap + (size_t)(ar + 64) * K + k0 + ac,   As + (ar + 64) * 32 + ac);
        #pragma unroll
        for (int i = 0; i < BN / 64; ++i)
            gload_lds16(Bp + (size_t)(ar + i * 64) * K + k0 + ac, Bs + (ar + i * 64) * 32 + ac);
        __syncthreads();

        bf16x8 af[4], bfr[NFRAG];
        #pragma unroll
        for (int i = 0; i < 4; ++i)
            af[i] = *(const bf16x8*)(As + (wr * 64 + i * 16 + lr) * 32 + lk);
        #pragma unroll
        for (int j = 0; j < NFRAG; ++j)
            bfr[j] = *(const bf16x8*)(Bs + (wc * (BN / 2) + j * 16 + lr) * 32 + lk);
        #pragma unroll
        for (int i = 0; i < 4; ++i)
            #pragma unroll
            for (int j = 0; j < NFRAG; ++j)
                acc[i][j] = __builtin_amdgcn_mfma_f32_16x16x32_bf16(af[i], bfr[j], acc[i][j], 0, 0, 0);
    }

    const int rbase = (lane >> 4) * 4;
    if (MODE == 0) {
        __bf16* C = (__bf16*)Cout + (size_t)b * M * N;
        #pragma unroll
        for (int i = 0; i < 4; ++i)
            #pragma unroll
            for (int r = 0; r < 4; ++r) {
                const int m = m0 + wr * 64 + i * 16 + rbase + r;
                #pragma unroll
                for (int j = 0; j < NFRAG; ++j) {
                    const int n = n0 + wc * (BN / 2) + j * 16 + lr;
                    if (n < N) C[(size_t)m * N + n] = (__bf16)acc[i][j][r];
                }
            }
    } else {
        float* C = (float*)Cout + (size_t)b * M * N;
        #pragma unroll
        for (int i = 0; i < 4; ++i)
            #pragma unroll
            for (int r = 0; r < 4; ++r) {
                const int m = m0 + wr * 64 + i * 16 + rbase + r;
                const float sc = bn_g[m] * rsqrtf(bn_v[m] + 1e-5f);
                const float mu = bn_m[m], bb = bn_b[m];
                #pragma unroll
                for (int j = 0; j < NFRAG; ++j) {
                    const int n = n0 + wc * (BN / 2) + j * 16 + lr;
                    if (n < N) C[(size_t)m * N + n] = (acc[i][j][r] - mu) * sc + bb;
                }
            }
    }
}

// ---------------------------------------------------------------------------
// Fused depthwise 5x5 (pad 2) + grouped pointwise (8->8), v5.
// v4 -> v5: 7-row slabs.  LDS 17.9 KB -> 8 blocks/CU (32-wave cap), grid
// 6144 blocks (24/CU pool), dw serial chain halved (7 rows).  Out-of-range
// rows zeroed inline in the fill loop.  Costs ~20% halo over-read.
// ---------------------------------------------------------------------------
__global__ __launch_bounds__(256) void dwpw4(
    const __bf16* __restrict__ in, const float* __restrict__ wdw,
    const float* __restrict__ wpw, __bf16* __restrict__ out)
{
    __shared__ __bf16 tin[8][11][60];    // 10,560 B
    __shared__ __bf16 tdw[8][392];       //  6,272 B  (7*56)
    __shared__ float  wdws[8][25];       //    800 B
    __shared__ float  wpws[64];          //    256 B
    const int slab = blockIdx.x, g = blockIdx.y, b = blockIdx.z;
    const int y0 = slab * 7;
    const int tid = threadIdx.x;
    const __bf16* __restrict__ ip = in + ((size_t)b * 768 + g * 8) * NPIX;

    // lateral halo zero: cols {0,1,58,59} x 11 rows x 8 ch = 352
    for (int i = tid; i < 352; i += 256) {
        const int ch = i / 44, rem = i % 44, r = rem >> 2, cc = rem & 3;
        tin[ch][r][(cc < 2) ? cc : 56 + cc] = (__bf16)0.f;
    }
    if (tid < 200) ((float*)wdws)[tid] = wdw[g * 200 + tid];
    if (tid < 64)  wpws[tid] = wpw[g * 64 + tid];

    // interior fill (zeroing out-of-range rows inline): 8ch x 11r x 7oct = 616
    for (int i = tid; i < 616; i += 256) {
        const int ch = i / 77, rem = i % 77;
        const int yr = rem / 7, oct = rem % 7;
        const int y = y0 + yr - 2;
        __bf16* d = &tin[ch][yr][2 + oct * 8];
        if (y >= 0 && y < HGT) {
            bf16x8 v = *(const bf16x8*)&ip[(size_t)ch * NPIX + y * WID + oct * 8];
            #pragma unroll
            for (int j = 0; j < 4; ++j)
                *(bf16x2*)&d[j * 2] = (bf16x2){v[j * 2], v[j * 2 + 1]};
        } else {
            #pragma unroll
            for (int j = 0; j < 4; ++j)
                *(bf16x2*)&d[j * 2] = (bf16x2){(__bf16)0.f, (__bf16)0.f};
        }
    }
    __syncthreads();

    // depthwise: 224 tasks (ch, x-pair), single balanced round, 7 rows each
    if (tid < 224) {
        const int ch = tid / 28, x = (tid % 28) * 2;
        float wv[25];
        #pragma unroll
        for (int j = 0; j < 25; ++j) wv[j] = wdws[ch][j];
        float win[5][6];
        #pragma unroll
        for (int r = 0; r < 4; ++r)
            #pragma unroll
            for (int p = 0; p < 3; ++p) {
                bf16x2 t = *(const bf16x2*)&tin[ch][r][x + p * 2];
                win[r][p * 2] = (float)t[0];
                win[r][p * 2 + 1] = (float)t[1];
            }
        #pragma unroll
        for (int rr = 0; rr < 7; ++rr) {
            #pragma unroll
            for (int p = 0; p < 3; ++p) {
                bf16x2 t = *(const bf16x2*)&tin[ch][rr + 4][x + p * 2];
                win[4][p * 2] = (float)t[0];
                win[4][p * 2 + 1] = (float)t[1];
            }
            float s0 = 0.f, s1 = 0.f;
            #pragma unroll
            for (int r = 0; r < 5; ++r)
                #pragma unroll
                for (int cc = 0; cc < 5; ++cc) {
                    s0 += win[r][cc] * wv[r * 5 + cc];
                    s1 += win[r][cc + 1] * wv[r * 5 + cc];
                }
            *(bf16x2*)&tdw[ch][rr * 56 + x] = (bf16x2){(__bf16)s0, (__bf16)s1};
            #pragma unroll
            for (int r = 0; r < 4; ++r)
                #pragma unroll
                for (int cc = 0; cc < 6; ++cc)
                    win[r][cc] = win[r + 1][cc];
        }
    }
    __syncthreads();

    // grouped pointwise on the slab: 49 octet tasks, fully vectorized
    __bf16* __restrict__ op = out + ((size_t)b * 768 + g * 8) * NPIX + y0 * WID;
    for (int oct = tid; oct < 49; oct += 256) {
        const int p = oct * 8;
        float xi[8][8];
        #pragma unroll
        for (int i2 = 0; i2 < 8; ++i2) {
            bf16x8 v = *(const bf16x8*)&tdw[i2][p];
            #pragma unroll
            for (int j = 0; j < 8; ++j) xi[i2][j] = (float)v[j];
        }
        #pragma unroll
        for (int o = 0; o < 8; ++o) {
            bf16x8 ov;
            #pragma unroll
            for (int j = 0; j < 8; ++j) {
                float s = 0.f;
                #pragma unroll
                for (int i2 = 0; i2 < 8; ++i2) s += wpws[o * 8 + i2] * xi[i2][j];
                ov[j] = (__bf16)s;
            }
            *(bf16x8*)&op[(size_t)o * NPIX + p] = ov;
        }
    }
}

// ---------------------------------------------------------------------------
// Attention stage A v4b: kv via MFMA, vectorized loads, 4 pixel chunks.
// ---------------------------------------------------------------------------
__global__ __launch_bounds__(256) void attn_kv4(
    const __bf16* __restrict__ qkvb, const __bf16* __restrict__ pwb,
    const float* __restrict__ pos, const float* __restrict__ s1p,
    float* __restrict__ kvpart)
{
    __shared__ __bf16 kl[4][9][256];     // 4.5 KB / wave
    __shared__ __bf16 vl[4][9][256];
    __shared__ float red[4][16][16];
    const int chunk = blockIdx.x;        // 0..3
    const int h = blockIdx.y, b = blockIdx.z;
    const __bf16* __restrict__ src = (h < 32)
        ? qkvb + ((size_t)b * 768 + h * 24) * NPIX
        : pwb  + ((size_t)b * 768 + (h - 32) * 24) * NPIX;
    const float* __restrict__ pp = pos + (size_t)(h * 8) * NPIX;
    const float s1 = s1p[0];
    const int tid = threadIdx.x, lane = tid & 63, wid = tid >> 6;
    const int tbase = chunk * 12;
    const int nt = (chunk == 3) ? 13 : 12;   // 12*3+13 = 49 tiles = 3136 px
    const int lr = lane & 15, g = lane >> 4;

    __bf16 (*K)[256] = kl[wid];
    __bf16 (*V)[256] = vl[wid];

    {
        bf16x4 s1q, oneq;
        #pragma unroll
        for (int j = 0; j < 4; ++j) { s1q[j] = (__bf16)s1; oneq[j] = (__bf16)1.0f; }
        *(bf16x4*)&K[8][lane * 4] = s1q;
        *(bf16x4*)&V[8][lane * 4] = oneq;
    }

    f32x4 acc = {};

    for (int r = wid; r * 4 < nt; r += 4) {
        const int T = min(4, nt - r * 4);
        if (lane < T * 16) {
            const int n = (tbase + r * 4) * 64 + lane * 4;
            bf16x4 kr[8], vr[8];
            f32x4 pr[8];
            #pragma unroll
            for (int c = 0; c < 8; ++c) {
                kr[c] = *(const bf16x4*)&src[(size_t)(8 + c) * NPIX + n];
                pr[c] = *(const f32x4*)&pp[(size_t)c * NPIX + n];
                vr[c] = *(const bf16x4*)&src[(size_t)(16 + c) * NPIX + n];
            }
            float k1[8][4];
            #pragma unroll
            for (int j = 0; j < 4; ++j) {
                float u[8], s2 = 0.f;
                #pragma unroll
                for (int c = 0; c < 8; ++c) {
                    float kk = (float)kr[c][j] + pr[c][j];
                    u[c] = kk * kk;
                    s2 += u[c] * u[c];
                }
                float inv = 1.f / (sqrtf(s2) + 1e-15f);
                #pragma unroll
                for (int c = 0; c < 8; ++c) k1[c][j] = u[c] * inv;
            }
            const int px  = lane * 4;
            const int tb  = px & ~63;
            const int oct = (px >> 3) & 7;
            const int sub = px & 7;
            #pragma unroll
            for (int c = 0; c < 8; ++c) {
                bf16x4 kq;
                #pragma unroll
                for (int j = 0; j < 4; ++j) kq[j] = (__bf16)k1[c][j];
                *(bf16x4*)&K[c][tb + ((oct ^ c) << 3) + sub] = kq;
                *(bf16x4*)&V[c][tb + ((oct ^ c) << 3) + sub] = vr[c];
            }
        }
        for (int t = 0; t < T; ++t) {
            #pragma unroll
            for (int s = 0; s < 2; ++s) {
                const int off = t * 64 + (((s * 4 + g) ^ (lr & 7)) << 3);
                bf16x8 a = *(const bf16x8*)&K[lr][off];
                bf16x8 bb = *(const bf16x8*)&V[lr][off];
                acc = __builtin_amdgcn_mfma_f32_16x16x32_bf16(a, bb, acc, 0, 0, 0);
            }
        }
    }

    #pragma unroll
    for (int r = 0; r < 4; ++r) red[wid][g * 4 + r][lr] = acc[r];
    __syncthreads();
    if (tid < 81) {
        const int c = tid / 9, d = tid % 9;
        kvpart[((size_t)chunk * 512 + b * 64 + h) * 81 + tid]
            = red[0][c][d] + red[1][c][d] + red[2][c][d] + red[3][c][d];
    }
}

// ---------------------------------------------------------------------------
// Attention stage B v6: block = 64 px x 8 heads (2 heads/wave); grid
// (49,8,8)=3136 blocks; LDS 10.6 KB.  Fast tanh-GELU.  Sums 4 kv partials.
// ---------------------------------------------------------------------------
__global__ __launch_bounds__(256) void attn_out6(
    const __bf16* __restrict__ qkvb, const __bf16* __restrict__ pwb,
    const float* __restrict__ kvpart,
    const float* __restrict__ bng, const float* __restrict__ bnb,
    const float* __restrict__ bnm, const float* __restrict__ bnv,
    const float* __restrict__ s1p, __bf16* __restrict__ attb)
{
    __shared__ float kvs[8 * 81];        // 2.6 KB
    __shared__ __bf16 att[64 * 64];      // 8 KB: [px][8 heads * 8ch], swizzled
    const int b = blockIdx.z;
    const int hq0 = blockIdx.y * 8;      // head base (0,8,...,56)
    const int n0 = blockIdx.x * 64;
    const int tid = threadIdx.x, lane = tid & 63, wv_ = tid >> 6;
    const int n = n0 + lane;
    const float s1 = s1p[0];

    const int S = 512 * 81;
    for (int i = tid; i < 8 * 81; i += 256) {
        const size_t off = ((size_t)b * 64 + hq0) * 81 + i;
        kvs[i] = (kvpart[off] + kvpart[S + off])
               + (kvpart[2 * S + off] + kvpart[3 * S + off]);
    }
    __syncthreads();

    float bsc[8], bmu[8], bbe[8];
    #pragma unroll
    for (int d = 0; d < 8; ++d) {
        bsc[d] = bng[d] * rsqrtf(bnv[d] + 1e-5f);
        bmu[d] = bnm[d];
        bbe[d] = bnb[d];
    }

    #pragma unroll
    for (int hh = 0; hh < 2; ++hh) {
        const int hl = wv_ * 2 + hh;     // local head 0..7
        const int h = hq0 + hl;
        const __bf16* __restrict__ src = (h < 32)
            ? qkvb + ((size_t)b * 768 + h * 24) * NPIX
            : pwb  + ((size_t)b * 768 + (h - 32) * 24) * NPIX;
        const float* __restrict__ kvh = &kvs[hl * 81];

        // q1 = l2n(l2n(q)^2) = q^2 / ||q^2||  (exact identity)
        float q1[9], s2 = 0.f;
        #pragma unroll
        for (int c = 0; c < 8; ++c) {
            float qq = (float)src[(size_t)c * NPIX + n];
            q1[c] = qq * qq;
            s2 += q1[c] * q1[c];
        }
        float inv = 1.f / (sqrtf(s2) + 1e-15f);
        #pragma unroll
        for (int c = 0; c < 8; ++c) q1[c] *= inv;
        q1[8] = s1;

        float den = 0.f;
        #pragma unroll
        for (int c = 0; c < 9; ++c) den += q1[c] * kvh[c * 9 + 8];
        const float invd = 1.f / (den + 1e-15f);

        bf16x8 o;
        #pragma unroll
        for (int d = 0; d < 8; ++d) {
            float num = 0.f;
            #pragma unroll
            for (int c = 0; c < 9; ++c) num += q1[c] * kvh[c * 9 + d];
            float v = (float)src[(size_t)(16 + d) * NPIX + n];
            float fmv = (v - bmu[d]) * bsc[d] + bbe[d];
            o[d] = (__bf16)(num * invd + fast_gelu(fmv));
        }
        *(bf16x8*)((char*)att + lane * 128 + ((hl * 16) ^ ((lane & 7) << 4))) = o;
    }
    __syncthreads();

    #pragma unroll
    for (int p = 0; p < 2; ++p) {
        const int px = p * 32 + (tid >> 3);
        const int s = tid & 7;
        bf16x8 o = *(const bf16x8*)((const char*)att + px * 128 + ((s * 16) ^ ((px & 7) << 4)));
        *(bf16x8*)&attb[((size_t)b * NPIX + n0 + px) * 512 + hq0 * 8 + s * 8] = o;
    }
}

// ---------------------------------------------------------------------------
extern "C" void kernel_launch(void* const* d_in, const int* in_sizes, int n_in,
                              void* d_out, int out_size, void* d_ws, size_t ws_size,
                              hipStream_t stream)
{
    const float* x      = (const float*)d_in[0];
    const float* w_qkv  = (const float*)d_in[1];
    const float* w_dw   = (const float*)d_in[2];
    const float* w_pw   = (const float*)d_in[3];
    const float* pos    = (const float*)d_in[4];
    const float* s1     = (const float*)d_in[5];
    const float* bng    = (const float*)d_in[6];
    const float* bnb    = (const float*)d_in[7];
    const float* bnm    = (const float*)d_in[8];
    const float* bnv    = (const float*)d_in[9];
    const float* w_proj = (const float*)d_in[10];
    const float* pg     = (const float*)d_in[11];
    const float* pb     = (const float*)d_in[12];
    const float* pm     = (const float*)d_in[13];
    const float* pv     = (const float*)d_in[14];
    float* out = (float*)d_out;

    char* w = (char*)d_ws;
    __bf16* xT    = (__bf16*)(w);                       // 13,107,200
    __bf16* qkvb  = (__bf16*)(w + 13107200);            // 38,535,168
    __bf16* pwb   = (__bf16*)(w + 51642368);            // 38,535,168
    __bf16* attb  = (__bf16*)(w + 90177536);            // 25,690,112
    float*  kvpart= (float*) (w + 115867648);           // 4*512*81*4 = 663,552
    __bf16* wq_bf = (__bf16*)(w + 116531200);           // 393,216
    __bf16* wp_bf = (__bf16*)(w + 116924416);           // 262,144

    wcvt<<<768, 256, 0, stream>>>(w_qkv, w_proj, wq_bf, wp_bf);
    xpose_cvt<<<dim3(100, 8, 8), 256, 0, stream>>>(x, xT);

    // qkv = w_qkv(768x256) @ x  -> bf16 planar [8][768][3136]
    gemm1x1<128, 0><<<dim3(1200), 256, 0, stream>>>(
        wq_bf, xT, qkvb, 768, 256, NPIX, NPAD, 25, 6,
        nullptr, nullptr, nullptr, nullptr);

    // fused depthwise 5x5 + grouped pointwise -> pwb (no dwb round-trip)
    dwpw4<<<dim3(8, 96, 8), 256, 0, stream>>>(qkvb, w_dw, w_pw, pwb);

    attn_kv4<<<dim3(4, 64, 8), 256, 0, stream>>>(qkvb, pwb, pos, s1, kvpart);
    attn_out6<<<dim3(49, 8, 8), 256, 0, stream>>>(
        qkvb, pwb, kvpart, bng, bnb, bnm, bnv, s1, attb);

    // out = w_proj(256x512) @ attb^T + BN -> f32 planar [8][256][3136]
    gemm1x1<64, 1><<<dim3(784), 256, 0, stream>>>(
        wp_bf, attb, out, 256, 512, NPIX, NPIX, 49, 2,
        pg, pb, pm, pv);
}

// Round 16
// 122.590 us; speedup vs baseline: 1.0344x; 1.0344x over previous
//
#include <hip/hip_runtime.h>
#include <cstdint>

#define NPIX 3136
#define HGT 56
#define WID 56
#define NPAD 3200   // padded pixel count for BM=128 tiling

typedef __bf16 bf16x8 __attribute__((ext_vector_type(8)));
typedef __bf16 bf16x4 __attribute__((ext_vector_type(4)));
typedef __bf16 bf16x2 __attribute__((ext_vector_type(2)));
typedef float  f32x4  __attribute__((ext_vector_type(4)));
typedef float  f32x2  __attribute__((ext_vector_type(2)));

typedef const __attribute__((address_space(1))) unsigned int* gptr_t;
typedef __attribute__((address_space(3))) unsigned int* lptr_t;

__device__ __forceinline__ void gload_lds16(const __bf16* g, __bf16* l) {
    __builtin_amdgcn_global_load_lds((gptr_t)(const void*)g, (lptr_t)(void*)l, 16, 0, 0);
}

// tanh-form GELU, |err vs exact gelu| < ~3e-3 (threshold is 4.9e-2)
__device__ __forceinline__ float fast_gelu(float x) {
    float y = 0.7978845608f * x * (1.f + 0.044715f * x * x);
    float t = __expf(-2.f * fabsf(y));
    float th = (1.f - t) * __builtin_amdgcn_rcpf(1.f + t);
    th = copysignf(th, y);
    return 0.5f * x * (1.f + th);
}

// ---------------------------------------------------------------------------
// Convert both weight matrices to bf16 (row-major, k contiguous).
// ---------------------------------------------------------------------------
__global__ __launch_bounds__(256) void wcvt(
    const float* __restrict__ wq, const float* __restrict__ wp,
    __bf16* __restrict__ oq, __bf16* __restrict__ op)
{
    int i = blockIdx.x * 256 + threadIdx.x;
    if (i < 768 * 256) oq[i] = (__bf16)wq[i];
    if (i < 256 * 512) op[i] = (__bf16)wp[i];
}

// ---------------------------------------------------------------------------
// x [8][256][3136] f32 -> xT [8][3200][256] bf16 (n-major), zero-padded rows.
// ---------------------------------------------------------------------------
__global__ __launch_bounds__(256) void xpose_cvt(
    const float* __restrict__ x, __bf16* __restrict__ xT)
{
    __shared__ float t[32][33];
    const int n0 = blockIdx.x * 32;
    const int k0 = blockIdx.y * 32;
    const int b  = blockIdx.z;
    const int tid = threadIdx.x;
    const int ln = tid & 31, lk = tid >> 5;
    #pragma unroll
    for (int r = 0; r < 4; ++r) {
        int n = n0 + ln, k = k0 + lk + r * 8;
        t[lk + r * 8][ln] = (n < NPIX) ? x[((size_t)b * 256 + k) * NPIX + n] : 0.f;
    }
    __syncthreads();
    const int nr = tid >> 3, kc = (tid & 7) * 4;
    bf16x4 o;
    #pragma unroll
    for (int i = 0; i < 4; ++i) o[i] = (__bf16)t[kc + i][nr];
    *(bf16x4*)&xT[((size_t)b * NPAD + n0 + nr) * 256 + k0 + kc] = o;
}

// ---------------------------------------------------------------------------
// bf16 MFMA GEMM: C[b][m][n] = sum_k A[m][k] * B[b][n][k]
// BM=128, BK=32, 4 waves. MODE 0: bf16 planar out.  MODE 1: f32 + BN.
// Flat 1-D grid, XCD-co-location decode.
// ---------------------------------------------------------------------------
template<int BN, int MODE>
__global__ __launch_bounds__(256) void gemm1x1(
    const __bf16* __restrict__ A,   // [M][K]
    const __bf16* __restrict__ Bm,  // [batch][NP][K]
    void* __restrict__ Cout,
    const int M, const int K, const int N, const int NP,
    const int NT, const int MT,
    const float* __restrict__ bn_g, const float* __restrict__ bn_b,
    const float* __restrict__ bn_m, const float* __restrict__ bn_v)
{
    constexpr int NFRAG = BN / 32;
    __shared__ __bf16 As[128 * 32];
    __shared__ __bf16 Bs[BN * 32];
    const int tid = threadIdx.x;

    // XCD-co-location decode
    const int F = blockIdx.x;
    const int gpb = MT * 8;
    const int A_ = F / gpb, R_ = F % gpb;
    const int mi = R_ >> 3, ci = R_ & 7;
    const int g_ = A_ * 8 + ci;
    const int n0 = (g_ % NT) * BN;
    const int b  = g_ / NT;
    const int m0 = mi * 128;

    const int lane = tid & 63, wid = tid >> 6;
    const int wr = wid >> 1, wc = wid & 1;
    const int lr = lane & 15, lk = (lane >> 4) * 8;

    f32x4 acc[4][NFRAG] = {};
    const __bf16* Ap = A + (size_t)m0 * K;
    const __bf16* Bp = Bm + ((size_t)b * NP + n0) * K;
    const int ar = tid >> 2, ac = (tid & 3) * 8;

    for (int k0 = 0; k0 < K; k0 += 32) {
        __syncthreads();
        gload_lds16(Ap + (size_t)ar * K + k0 + ac,          As + ar * 32 + ac);
        gload_lds16(Ap + (size_t)(ar + 64) * K + k0 + ac,   As + (ar + 64) * 32 + ac);
        #pragma unroll
        for (int i = 0; i < BN / 64; ++i)
            gload_lds16(Bp + (size_t)(ar + i * 64) * K + k0 + ac, Bs + (ar + i * 64) * 32 + ac);
        __syncthreads();

        bf16x8 af[4], bfr[NFRAG];
        #pragma unroll
        for (int i = 0; i < 4; ++i)
            af[i] = *(const bf16x8*)(As + (wr * 64 + i * 16 + lr) * 32 + lk);
        #pragma unroll
        for (int j = 0; j < NFRAG; ++j)
            bfr[j] = *(const bf16x8*)(Bs + (wc * (BN / 2) + j * 16 + lr) * 32 + lk);
        #pragma unroll
        for (int i = 0; i < 4; ++i)
            #pragma unroll
            for (int j = 0; j < NFRAG; ++j)
                acc[i][j] = __builtin_amdgcn_mfma_f32_16x16x32_bf16(af[i], bfr[j], acc[i][j], 0, 0, 0);
    }

    const int rbase = (lane >> 4) * 4;
    if (MODE == 0) {
        __bf16* C = (__bf16*)Cout + (size_t)b * M * N;
        #pragma unroll
        for (int i = 0; i < 4; ++i)
            #pragma unroll
            for (int r = 0; r < 4; ++r) {
                const int m = m0 + wr * 64 + i * 16 + rbase + r;
                #pragma unroll
                for (int j = 0; j < NFRAG; ++j) {
                    const int n = n0 + wc * (BN / 2) + j * 16 + lr;
                    if (n < N) C[(size_t)m * N + n] = (__bf16)acc[i][j][r];
                }
            }
    } else {
        float* C = (float*)Cout + (size_t)b * M * N;
        #pragma unroll
        for (int i = 0; i < 4; ++i)
            #pragma unroll
            for (int r = 0; r < 4; ++r) {
                const int m = m0 + wr * 64 + i * 16 + rbase + r;
                const float sc = bn_g[m] * rsqrtf(bn_v[m] + 1e-5f);
                const float mu = bn_m[m], bb = bn_b[m];
                #pragma unroll
                for (int j = 0; j < NFRAG; ++j) {
                    const int n = n0 + wc * (BN / 2) + j * 16 + lr;
                    if (n < N) C[(size_t)m * N + n] = (acc[i][j][r] - mu) * sc + bb;
                }
            }
    }
}

// ---------------------------------------------------------------------------
// Fused depthwise 5x5 (pad 2) + grouped pointwise (8->8), v6.
// = v4 (14-row slab, bf16 tile, 2-px tasks — best measured) + 4-way split
// accumulators in the dw loop (dependency depth 25 -> ~13 FMA per chain).
// ---------------------------------------------------------------------------
__global__ __launch_bounds__(256) void dwpw3(
    const __bf16* __restrict__ in, const float* __restrict__ wdw,
    const float* __restrict__ wpw, __bf16* __restrict__ out)
{
    __shared__ __bf16 tin[8][18][60];    // 17,280 B
    __shared__ __bf16 tdw[8][784];       // 12,544 B  (14*56)
    __shared__ float  wdws[8][25];       // 800 B
    __shared__ float  wpws[64];          // 256 B
    const int slab = blockIdx.x, g = blockIdx.y, b = blockIdx.z;
    const int y0 = slab * 14;
    const int tid = threadIdx.x;
    const __bf16* __restrict__ ip = in + ((size_t)b * 768 + g * 8) * NPIX;

    // halo-only zero: lateral 2-col strips (cols 0,1,58,59) x 18 rows x 8 ch
    for (int i = tid; i < 576; i += 256) {
        const int ch = i / 72, rem = i % 72, r = rem >> 2, cc = rem & 3;
        tin[ch][r][(cc < 2) ? cc : 56 + cc] = (__bf16)0.f;
    }
    // top/bottom out-of-range rows (boundary slabs only): 8ch x 2rows x 60
    if (y0 == 0 || y0 == 42) {
        const int rbase = (y0 == 0) ? 0 : 16;
        for (int i = tid; i < 960; i += 256) {
            const int ch = i / 120, rem = i % 120, r = rem / 60, c = rem % 60;
            tin[ch][rbase + r][c] = (__bf16)0.f;
        }
    }
    if (tid < 200) ((float*)wdws)[tid] = wdw[g * 200 + tid];
    if (tid < 64)  wpws[tid] = wpw[g * 64 + tid];

    // interior fill: 8ch x 18 rows x 7 octets = 1008 copy tasks (no cvt)
    for (int i = tid; i < 1008; i += 256) {
        const int ch = i / 126, rem = i % 126;
        const int yr = rem / 7, oct = rem % 7;
        const int y = y0 + yr - 2;
        if (y >= 0 && y < HGT) {
            bf16x8 v = *(const bf16x8*)&ip[(size_t)ch * NPIX + y * WID + oct * 8];
            __bf16* d = &tin[ch][yr][2 + oct * 8];
            #pragma unroll
            for (int j = 0; j < 4; ++j)
                *(bf16x2*)&d[j * 2] = (bf16x2){v[j * 2], v[j * 2 + 1]};
        }
    }
    __syncthreads();

    // depthwise: 224 tasks (ch, x-pair), single round, 4 independent FMA chains
    if (tid < 224) {
        const int ch = tid / 28, x = (tid % 28) * 2;
        float wv[25];
        #pragma unroll
        for (int j = 0; j < 25; ++j) wv[j] = wdws[ch][j];
        float win[5][6];
        #pragma unroll
        for (int r = 0; r < 4; ++r)
            #pragma unroll
            for (int p = 0; p < 3; ++p) {
                bf16x2 t = *(const bf16x2*)&tin[ch][r][x + p * 2];
                win[r][p * 2] = (float)t[0];
                win[r][p * 2 + 1] = (float)t[1];
            }
        #pragma unroll
        for (int rr = 0; rr < 14; ++rr) {
            #pragma unroll
            for (int p = 0; p < 3; ++p) {
                bf16x2 t = *(const bf16x2*)&tin[ch][rr + 4][x + p * 2];
                win[4][p * 2] = (float)t[0];
                win[4][p * 2 + 1] = (float)t[1];
            }
            float s0a = 0.f, s0b = 0.f, s1a = 0.f, s1b = 0.f;
            #pragma unroll
            for (int r = 0; r < 3; ++r)
                #pragma unroll
                for (int cc = 0; cc < 5; ++cc) {
                    s0a += win[r][cc] * wv[r * 5 + cc];
                    s1a += win[r][cc + 1] * wv[r * 5 + cc];
                }
            #pragma unroll
            for (int r = 3; r < 5; ++r)
                #pragma unroll
                for (int cc = 0; cc < 5; ++cc) {
                    s0b += win[r][cc] * wv[r * 5 + cc];
                    s1b += win[r][cc + 1] * wv[r * 5 + cc];
                }
            *(bf16x2*)&tdw[ch][rr * 56 + x] =
                (bf16x2){(__bf16)(s0a + s0b), (__bf16)(s1a + s1b)};
            #pragma unroll
            for (int r = 0; r < 4; ++r)
                #pragma unroll
                for (int cc = 0; cc < 6; ++cc)
                    win[r][cc] = win[r + 1][cc];
        }
    }
    __syncthreads();

    // grouped pointwise on the slab: 98 octet tasks, fully vectorized
    __bf16* __restrict__ op = out + ((size_t)b * 768 + g * 8) * NPIX + y0 * WID;
    for (int oct = tid; oct < 98; oct += 256) {
        const int p = oct * 8;
        float xi[8][8];
        #pragma unroll
        for (int i2 = 0; i2 < 8; ++i2) {
            bf16x8 v = *(const bf16x8*)&tdw[i2][p];
            #pragma unroll
            for (int j = 0; j < 8; ++j) xi[i2][j] = (float)v[j];
        }
        #pragma unroll
        for (int o = 0; o < 8; ++o) {
            bf16x8 ov;
            #pragma unroll
            for (int j = 0; j < 8; ++j) {
                float s = 0.f;
                #pragma unroll
                for (int i2 = 0; i2 < 8; ++i2) s += wpws[o * 8 + i2] * xi[i2][j];
                ov[j] = (__bf16)s;
            }
            *(bf16x8*)&op[(size_t)o * NPIX + p] = ov;
        }
    }
}

// ---------------------------------------------------------------------------
// Attention stage A v4b: kv via MFMA, vectorized loads, 4 pixel chunks.
// ---------------------------------------------------------------------------
__global__ __launch_bounds__(256) void attn_kv4(
    const __bf16* __restrict__ qkvb, const __bf16* __restrict__ pwb,
    const float* __restrict__ pos, const float* __restrict__ s1p,
    float* __restrict__ kvpart)
{
    __shared__ __bf16 kl[4][9][256];     // 4.5 KB / wave
    __shared__ __bf16 vl[4][9][256];
    __shared__ float red[4][16][16];
    const int chunk = blockIdx.x;        // 0..3
    const int h = blockIdx.y, b = blockIdx.z;
    const __bf16* __restrict__ src = (h < 32)
        ? qkvb + ((size_t)b * 768 + h * 24) * NPIX
        : pwb  + ((size_t)b * 768 + (h - 32) * 24) * NPIX;
    const float* __restrict__ pp = pos + (size_t)(h * 8) * NPIX;
    const float s1 = s1p[0];
    const int tid = threadIdx.x, lane = tid & 63, wid = tid >> 6;
    const int tbase = chunk * 12;
    const int nt = (chunk == 3) ? 13 : 12;   // 12*3+13 = 49 tiles = 3136 px
    const int lr = lane & 15, g = lane >> 4;

    __bf16 (*K)[256] = kl[wid];
    __bf16 (*V)[256] = vl[wid];

    {
        bf16x4 s1q, oneq;
        #pragma unroll
        for (int j = 0; j < 4; ++j) { s1q[j] = (__bf16)s1; oneq[j] = (__bf16)1.0f; }
        *(bf16x4*)&K[8][lane * 4] = s1q;
        *(bf16x4*)&V[8][lane * 4] = oneq;
    }

    f32x4 acc = {};

    for (int r = wid; r * 4 < nt; r += 4) {
        const int T = min(4, nt - r * 4);
        if (lane < T * 16) {
            const int n = (tbase + r * 4) * 64 + lane * 4;
            bf16x4 kr[8], vr[8];
            f32x4 pr[8];
            #pragma unroll
            for (int c = 0; c < 8; ++c) {
                kr[c] = *(const bf16x4*)&src[(size_t)(8 + c) * NPIX + n];
                pr[c] = *(const f32x4*)&pp[(size_t)c * NPIX + n];
                vr[c] = *(const bf16x4*)&src[(size_t)(16 + c) * NPIX + n];
            }
            float k1[8][4];
            #pragma unroll
            for (int j = 0; j < 4; ++j) {
                float u[8], s2 = 0.f;
                #pragma unroll
                for (int c = 0; c < 8; ++c) {
                    float kk = (float)kr[c][j] + pr[c][j];
                    u[c] = kk * kk;
                    s2 += u[c] * u[c];
                }
                float inv = 1.f / (sqrtf(s2) + 1e-15f);
                #pragma unroll
                for (int c = 0; c < 8; ++c) k1[c][j] = u[c] * inv;
            }
            const int px  = lane * 4;
            const int tb  = px & ~63;
            const int oct = (px >> 3) & 7;
            const int sub = px & 7;
            #pragma unroll
            for (int c = 0; c < 8; ++c) {
                bf16x4 kq;
                #pragma unroll
                for (int j = 0; j < 4; ++j) kq[j] = (__bf16)k1[c][j];
                *(bf16x4*)&K[c][tb + ((oct ^ c) << 3) + sub] = kq;
                *(bf16x4*)&V[c][tb + ((oct ^ c) << 3) + sub] = vr[c];
            }
        }
        for (int t = 0; t < T; ++t) {
            #pragma unroll
            for (int s = 0; s < 2; ++s) {
                const int off = t * 64 + (((s * 4 + g) ^ (lr & 7)) << 3);
                bf16x8 a = *(const bf16x8*)&K[lr][off];
                bf16x8 bb = *(const bf16x8*)&V[lr][off];
                acc = __builtin_amdgcn_mfma_f32_16x16x32_bf16(a, bb, acc, 0, 0, 0);
            }
        }
    }

    #pragma unroll
    for (int r = 0; r < 4; ++r) red[wid][g * 4 + r][lr] = acc[r];
    __syncthreads();
    if (tid < 81) {
        const int c = tid / 9, d = tid % 9;
        kvpart[((size_t)chunk * 512 + b * 64 + h) * 81 + tid]
            = red[0][c][d] + red[1][c][d] + red[2][c][d] + red[3][c][d];
    }
}

// ---------------------------------------------------------------------------
// Attention stage B v6: block = 64 px x 8 heads (2 heads/wave); grid
// (49,8,8)=3136 blocks; LDS 10.6 KB.  Fast tanh-GELU.  Sums 4 kv partials.
// ---------------------------------------------------------------------------
__global__ __launch_bounds__(256) void attn_out6(
    const __bf16* __restrict__ qkvb, const __bf16* __restrict__ pwb,
    const float* __restrict__ kvpart,
    const float* __restrict__ bng, const float* __restrict__ bnb,
    const float* __restrict__ bnm, const float* __restrict__ bnv,
    const float* __restrict__ s1p, __bf16* __restrict__ attb)
{
    __shared__ float kvs[8 * 81];        // 2.6 KB
    __shared__ __bf16 att[64 * 64];      // 8 KB: [px][8 heads * 8ch], swizzled
    const int b = blockIdx.z;
    const int hq0 = blockIdx.y * 8;      // head base (0,8,...,56)
    const int n0 = blockIdx.x * 64;
    const int tid = threadIdx.x, lane = tid & 63, wv_ = tid >> 6;
    const int n = n0 + lane;
    const float s1 = s1p[0];

    const int S = 512 * 81;
    for (int i = tid; i < 8 * 81; i += 256) {
        const size_t off = ((size_t)b * 64 + hq0) * 81 + i;
        kvs[i] = (kvpart[off] + kvpart[S + off])
               + (kvpart[2 * S + off] + kvpart[3 * S + off]);
    }
    __syncthreads();

    float bsc[8], bmu[8], bbe[8];
    #pragma unroll
    for (int d = 0; d < 8; ++d) {
        bsc[d] = bng[d] * rsqrtf(bnv[d] + 1e-5f);
        bmu[d] = bnm[d];
        bbe[d] = bnb[d];
    }

    #pragma unroll
    for (int hh = 0; hh < 2; ++hh) {
        const int hl = wv_ * 2 + hh;     // local head 0..7
        const int h = hq0 + hl;
        const __bf16* __restrict__ src = (h < 32)
            ? qkvb + ((size_t)b * 768 + h * 24) * NPIX
            : pwb  + ((size_t)b * 768 + (h - 32) * 24) * NPIX;
        const float* __restrict__ kvh = &kvs[hl * 81];

        // q1 = l2n(l2n(q)^2) = q^2 / ||q^2||  (exact identity)
        float q1[9], s2 = 0.f;
        #pragma unroll
        for (int c = 0; c < 8; ++c) {
            float qq = (float)src[(size_t)c * NPIX + n];
            q1[c] = qq * qq;
            s2 += q1[c] * q1[c];
        }
        float inv = 1.f / (sqrtf(s2) + 1e-15f);
        #pragma unroll
        for (int c = 0; c < 8; ++c) q1[c] *= inv;
        q1[8] = s1;

        float den = 0.f;
        #pragma unroll
        for (int c = 0; c < 9; ++c) den += q1[c] * kvh[c * 9 + 8];
        const float invd = 1.f / (den + 1e-15f);

        bf16x8 o;
        #pragma unroll
        for (int d = 0; d < 8; ++d) {
            float num = 0.f;
            #pragma unroll
            for (int c = 0; c < 9; ++c) num += q1[c] * kvh[c * 9 + d];
            float v = (float)src[(size_t)(16 + d) * NPIX + n];
            float fmv = (v - bmu[d]) * bsc[d] + bbe[d];
            o[d] = (__bf16)(num * invd + fast_gelu(fmv));
        }
        *(bf16x8*)((char*)att + lane * 128 + ((hl * 16) ^ ((lane & 7) << 4))) = o;
    }
    __syncthreads();

    #pragma unroll
    for (int p = 0; p < 2; ++p) {
        const int px = p * 32 + (tid >> 3);
        const int s = tid & 7;
        bf16x8 o = *(const bf16x8*)((const char*)att + px * 128 + ((s * 16) ^ ((px & 7) << 4)));
        *(bf16x8*)&attb[((size_t)b * NPIX + n0 + px) * 512 + hq0 * 8 + s * 8] = o;
    }
}

// ---------------------------------------------------------------------------
extern "C" void kernel_launch(void* const* d_in, const int* in_sizes, int n_in,
                              void* d_out, int out_size, void* d_ws, size_t ws_size,
                              hipStream_t stream)
{
    const float* x      = (const float*)d_in[0];
    const float* w_qkv  = (const float*)d_in[1];
    const float* w_dw   = (const float*)d_in[2];
    const float* w_pw   = (const float*)d_in[3];
    const float* pos    = (const float*)d_in[4];
    const float* s1     = (const float*)d_in[5];
    const float* bng    = (const float*)d_in[6];
    const float* bnb    = (const float*)d_in[7];
    const float* bnm    = (const float*)d_in[8];
    const float* bnv    = (const float*)d_in[9];
    const float* w_proj = (const float*)d_in[10];
    const float* pg     = (const float*)d_in[11];
    const float* pb     = (const float*)d_in[12];
    const float* pm     = (const float*)d_in[13];
    const float* pv     = (const float*)d_in[14];
    float* out = (float*)d_out;

    char* w = (char*)d_ws;
    __bf16* xT    = (__bf16*)(w);                       // 13,107,200
    __bf16* qkvb  = (__bf16*)(w + 13107200);            // 38,535,168
    __bf16* pwb   = (__bf16*)(w + 51642368);            // 38,535,168
    __bf16* attb  = (__bf16*)(w + 90177536);            // 25,690,112
    float*  kvpart= (float*) (w + 115867648);           // 4*512*81*4 = 663,552
    __bf16* wq_bf = (__bf16*)(w + 116531200);           // 393,216
    __bf16* wp_bf = (__bf16*)(w + 116924416);           // 262,144

    wcvt<<<768, 256, 0, stream>>>(w_qkv, w_proj, wq_bf, wp_bf);
    xpose_cvt<<<dim3(100, 8, 8), 256, 0, stream>>>(x, xT);

    // qkv = w_qkv(768x256) @ x  -> bf16 planar [8][768][3136]
    gemm1x1<128, 0><<<dim3(1200), 256, 0, stream>>>(
        wq_bf, xT, qkvb, 768, 256, NPIX, NPAD, 25, 6,
        nullptr, nullptr, nullptr, nullptr);

    // fused depthwise 5x5 + grouped pointwise -> pwb (no dwb round-trip)
    dwpw3<<<dim3(4, 96, 8), 256, 0, stream>>>(qkvb, w_dw, w_pw, pwb);

    attn_kv4<<<dim3(4, 64, 8), 256, 0, stream>>>(qkvb, pwb, pos, s1, kvpart);
    attn_out6<<<dim3(49, 8, 8), 256, 0, stream>>>(
        qkvb, pwb, kvpart, bng, bnb, bnm, bnv, s1, attb);

    // out = w_proj(256x512) @ attb^T + BN -> f32 planar [8][256][3136]
    gemm1x1<64, 1><<<dim3(784), 256, 0, stream>>>(
        wp_bf, attb, out, 256, 512, NPIX, NPIX, 49, 2,
        pg, pb, pm, pv);
}

// Round 17
// 121.894 us; speedup vs baseline: 1.0403x; 1.0057x over previous
//
#include <hip/hip_runtime.h>
#include <cstdint>

#define NPIX 3136
#define HGT 56
#define WID 56
#define NPAD 3200   // padded pixel count for BM=128 tiling

typedef __bf16 bf16x8 __attribute__((ext_vector_type(8)));
typedef __bf16 bf16x4 __attribute__((ext_vector_type(4)));
typedef __bf16 bf16x2 __attribute__((ext_vector_type(2)));
typedef float  f32x4  __attribute__((ext_vector_type(4)));
typedef float  f32x2  __attribute__((ext_vector_type(2)));
typedef _Float16 f16x2 __attribute__((ext_vector_type(2)));

typedef const __attribute__((address_space(1))) unsigned int* gptr_t;
typedef __attribute__((address_space(3))) unsigned int* lptr_t;

__device__ __forceinline__ void gload_lds16(const __bf16* g, __bf16* l) {
    __builtin_amdgcn_global_load_lds((gptr_t)(const void*)g, (lptr_t)(void*)l, 16, 0, 0);
}

// tanh-form GELU, |err vs exact gelu| < ~3e-3 (threshold is 4.9e-2)
__device__ __forceinline__ float fast_gelu(float x) {
    float y = 0.7978845608f * x * (1.f + 0.044715f * x * x);
    float t = __expf(-2.f * fabsf(y));
    float th = (1.f - t) * __builtin_amdgcn_rcpf(1.f + t);
    th = copysignf(th, y);
    return 0.5f * x * (1.f + th);
}

// ---------------------------------------------------------------------------
// Convert both weight matrices to bf16 (row-major, k contiguous).
// ---------------------------------------------------------------------------
__global__ __launch_bounds__(256) void wcvt(
    const float* __restrict__ wq, const float* __restrict__ wp,
    __bf16* __restrict__ oq, __bf16* __restrict__ op)
{
    int i = blockIdx.x * 256 + threadIdx.x;
    if (i < 768 * 256) oq[i] = (__bf16)wq[i];
    if (i < 256 * 512) op[i] = (__bf16)wp[i];
}

// ---------------------------------------------------------------------------
// x [8][256][3136] f32 -> xT [8][3200][256] bf16 (n-major), zero-padded rows.
// ---------------------------------------------------------------------------
__global__ __launch_bounds__(256) void xpose_cvt(
    const float* __restrict__ x, __bf16* __restrict__ xT)
{
    __shared__ float t[32][33];
    const int n0 = blockIdx.x * 32;
    const int k0 = blockIdx.y * 32;
    const int b  = blockIdx.z;
    const int tid = threadIdx.x;
    const int ln = tid & 31, lk = tid >> 5;
    #pragma unroll
    for (int r = 0; r < 4; ++r) {
        int n = n0 + ln, k = k0 + lk + r * 8;
        t[lk + r * 8][ln] = (n < NPIX) ? x[((size_t)b * 256 + k) * NPIX + n] : 0.f;
    }
    __syncthreads();
    const int nr = tid >> 3, kc = (tid & 7) * 4;
    bf16x4 o;
    #pragma unroll
    for (int i = 0; i < 4; ++i) o[i] = (__bf16)t[kc + i][nr];
    *(bf16x4*)&xT[((size_t)b * NPAD + n0 + nr) * 256 + k0 + kc] = o;
}

// ---------------------------------------------------------------------------
// bf16 MFMA GEMM: C[b][m][n] = sum_k A[m][k] * B[b][n][k]
// BM=128, BK=32, 4 waves. MODE 0: bf16 planar out.  MODE 1: f32 + BN.
// Flat 1-D grid, XCD-co-location decode.
// ---------------------------------------------------------------------------
template<int BN, int MODE>
__global__ __launch_bounds__(256) void gemm1x1(
    const __bf16* __restrict__ A,   // [M][K]
    const __bf16* __restrict__ Bm,  // [batch][NP][K]
    void* __restrict__ Cout,
    const int M, const int K, const int N, const int NP,
    const int NT, const int MT,
    const float* __restrict__ bn_g, const float* __restrict__ bn_b,
    const float* __restrict__ bn_m, const float* __restrict__ bn_v)
{
    constexpr int NFRAG = BN / 32;
    __shared__ __bf16 As[128 * 32];
    __shared__ __bf16 Bs[BN * 32];
    const int tid = threadIdx.x;

    // XCD-co-location decode
    const int F = blockIdx.x;
    const int gpb = MT * 8;
    const int A_ = F / gpb, R_ = F % gpb;
    const int mi = R_ >> 3, ci = R_ & 7;
    const int g_ = A_ * 8 + ci;
    const int n0 = (g_ % NT) * BN;
    const int b  = g_ / NT;
    const int m0 = mi * 128;

    const int lane = tid & 63, wid = tid >> 6;
    const int wr = wid >> 1, wc = wid & 1;
    const int lr = lane & 15, lk = (lane >> 4) * 8;

    f32x4 acc[4][NFRAG] = {};
    const __bf16* Ap = A + (size_t)m0 * K;
    const __bf16* Bp = Bm + ((size_t)b * NP + n0) * K;
    const int ar = tid >> 2, ac = (tid & 3) * 8;

    for (int k0 = 0; k0 < K; k0 += 32) {
        __syncthreads();
        gload_lds16(Ap + (size_t)ar * K + k0 + ac,          As + ar * 32 + ac);
        gload_lds16(Ap + (size_t)(ar + 64) * K + k0 + ac,   As + (ar + 64) * 32 + ac);
        #pragma unroll
        for (int i = 0; i < BN / 64; ++i)
            gload_lds16(Bp + (size_t)(ar + i * 64) * K + k0 + ac, Bs + (ar + i * 64) * 32 + ac);
        __syncthreads();

        bf16x8 af[4], bfr[NFRAG];
        #pragma unroll
        for (int i = 0; i < 4; ++i)
            af[i] = *(const bf16x8*)(As + (wr * 64 + i * 16 + lr) * 32 + lk);
        #pragma unroll
        for (int j = 0; j < NFRAG; ++j)
            bfr[j] = *(const bf16x8*)(Bs + (wc * (BN / 2) + j * 16 + lr) * 32 + lk);
        #pragma unroll
        for (int i = 0; i < 4; ++i)
            #pragma unroll
            for (int j = 0; j < NFRAG; ++j)
                acc[i][j] = __builtin_amdgcn_mfma_f32_16x16x32_bf16(af[i], bfr[j], acc[i][j], 0, 0, 0);
    }

    const int rbase = (lane >> 4) * 4;
    if (MODE == 0) {
        __bf16* C = (__bf16*)Cout + (size_t)b * M * N;
        #pragma unroll
        for (int i = 0; i < 4; ++i)
            #pragma unroll
            for (int r = 0; r < 4; ++r) {
                const int m = m0 + wr * 64 + i * 16 + rbase + r;
                #pragma unroll
                for (int j = 0; j < NFRAG; ++j) {
                    const int n = n0 + wc * (BN / 2) + j * 16 + lr;
                    if (n < N) C[(size_t)m * N + n] = (__bf16)acc[i][j][r];
                }
            }
    } else {
        float* C = (float*)Cout + (size_t)b * M * N;
        #pragma unroll
        for (int i = 0; i < 4; ++i)
            #pragma unroll
            for (int r = 0; r < 4; ++r) {
                const int m = m0 + wr * 64 + i * 16 + rbase + r;
                const float sc = bn_g[m] * rsqrtf(bn_v[m] + 1e-5f);
                const float mu = bn_m[m], bb = bn_b[m];
                #pragma unroll
                for (int j = 0; j < NFRAG; ++j) {
                    const int n = n0 + wc * (BN / 2) + j * 16 + lr;
                    if (n < N) C[(size_t)m * N + n] = (acc[i][j][r] - mu) * sc + bb;
                }
            }
    }
}

// ---------------------------------------------------------------------------
// Fused depthwise 5x5 (pad 2) + grouped pointwise (8->8), v7.
// v6 -> v7: f16 input tile + v_dot2_f32_f16 taps.  Per output row per 2 px:
// 3 aligned dword LDS loads + 6 dot2 (vs 3 loads + ~56 scalar VALU) — ~5x
// VALU cut in the dw phase.  Even/odd pixels share loads via two packed
// weight-pair register sets.  f16 has MORE mantissa than bf16 (accuracy up).
// ---------------------------------------------------------------------------
__global__ __launch_bounds__(256) void dwpw5(
    const __bf16* __restrict__ in, const float* __restrict__ wdw,
    const float* __restrict__ wpw, __bf16* __restrict__ out)
{
    __shared__ _Float16 tin[8][18][60];  // 17,280 B
    __shared__ __bf16   tdw[8][784];     // 12,544 B  (14*56)
    __shared__ float    wdws[8][25];     // 800 B
    __shared__ float    wpws[64];        // 256 B
    const int slab = blockIdx.x, g = blockIdx.y, b = blockIdx.z;
    const int y0 = slab * 14;
    const int tid = threadIdx.x;
    const __bf16* __restrict__ ip = in + ((size_t)b * 768 + g * 8) * NPIX;

    // halo-only zero: lateral 2-col strips (cols 0,1,58,59) x 18 rows x 8 ch
    for (int i = tid; i < 576; i += 256) {
        const int ch = i / 72, rem = i % 72, r = rem >> 2, cc = rem & 3;
        tin[ch][r][(cc < 2) ? cc : 56 + cc] = (_Float16)0.f;
    }
    // top/bottom out-of-range rows (boundary slabs only): 8ch x 2rows x 60
    if (y0 == 0 || y0 == 42) {
        const int rbase = (y0 == 0) ? 0 : 16;
        for (int i = tid; i < 960; i += 256) {
            const int ch = i / 120, rem = i % 120, r = rem / 60, c = rem % 60;
            tin[ch][rbase + r][c] = (_Float16)0.f;
        }
    }
    if (tid < 200) ((float*)wdws)[tid] = wdw[g * 200 + tid];
    if (tid < 64)  wpws[tid] = wpw[g * 64 + tid];

    // interior fill: 8ch x 18 rows x 7 octets = 1008 tasks (bf16 -> f16 cvt)
    for (int i = tid; i < 1008; i += 256) {
        const int ch = i / 126, rem = i % 126;
        const int yr = rem / 7, oct = rem % 7;
        const int y = y0 + yr - 2;
        if (y >= 0 && y < HGT) {
            bf16x8 v = *(const bf16x8*)&ip[(size_t)ch * NPIX + y * WID + oct * 8];
            _Float16* d = &tin[ch][yr][2 + oct * 8];
            #pragma unroll
            for (int j = 0; j < 4; ++j)
                *(f16x2*)&d[j * 2] =
                    (f16x2){(_Float16)(float)v[j * 2], (_Float16)(float)v[j * 2 + 1]};
        }
    }
    __syncthreads();

    // depthwise: 224 tasks (ch, x-pair), dot2 taps, packed sliding window
    if (tid < 224) {
        const int ch = tid / 28, x = (tid % 28) * 2;   // x even, cols x..x+5
        // packed weight pairs, both parities
        f16x2 we[5][3], wo[5][3];
        #pragma unroll
        for (int r = 0; r < 5; ++r) {
            float w0 = wdws[ch][r * 5 + 0], w1 = wdws[ch][r * 5 + 1],
                  w2 = wdws[ch][r * 5 + 2], w3 = wdws[ch][r * 5 + 3],
                  w4 = wdws[ch][r * 5 + 4];
            we[r][0] = (f16x2){(_Float16)w0, (_Float16)w1};
            we[r][1] = (f16x2){(_Float16)w2, (_Float16)w3};
            we[r][2] = (f16x2){(_Float16)w4, (_Float16)0.f};
            wo[r][0] = (f16x2){(_Float16)0.f, (_Float16)w0};
            wo[r][1] = (f16x2){(_Float16)w1, (_Float16)w2};
            wo[r][2] = (f16x2){(_Float16)w3, (_Float16)w4};
        }
        // packed window: 5 rows x 3 aligned pairs (cols x..x+5)
        f16x2 win[5][3];
        #pragma unroll
        for (int r = 0; r < 4; ++r)
            #pragma unroll
            for (int p = 0; p < 3; ++p)
                win[r][p] = *(const f16x2*)&tin[ch][r][x + p * 2];
        #pragma unroll
        for (int rr = 0; rr < 14; ++rr) {
            #pragma unroll
            for (int p = 0; p < 3; ++p)
                win[4][p] = *(const f16x2*)&tin[ch][rr + 4][x + p * 2];
            float s0 = 0.f, s1 = 0.f;
            #pragma unroll
            for (int r = 0; r < 5; ++r) {
                s0 = __builtin_amdgcn_fdot2(win[r][0], we[r][0], s0, false);
                s0 = __builtin_amdgcn_fdot2(win[r][1], we[r][1], s0, false);
                s0 = __builtin_amdgcn_fdot2(win[r][2], we[r][2], s0, false);
                s1 = __builtin_amdgcn_fdot2(win[r][0], wo[r][0], s1, false);
                s1 = __builtin_amdgcn_fdot2(win[r][1], wo[r][1], s1, false);
                s1 = __builtin_amdgcn_fdot2(win[r][2], wo[r][2], s1, false);
            }
            *(bf16x2*)&tdw[ch][rr * 56 + x] = (bf16x2){(__bf16)s0, (__bf16)s1};
            #pragma unroll
            for (int r = 0; r < 4; ++r)
                #pragma unroll
                for (int p = 0; p < 3; ++p)
                    win[r][p] = win[r + 1][p];
        }
    }
    __syncthreads();

    // grouped pointwise on the slab: 98 octet tasks, fully vectorized
    __bf16* __restrict__ op = out + ((size_t)b * 768 + g * 8) * NPIX + y0 * WID;
    for (int oct = tid; oct < 98; oct += 256) {
        const int p = oct * 8;
        float xi[8][8];
        #pragma unroll
        for (int i2 = 0; i2 < 8; ++i2) {
            bf16x8 v = *(const bf16x8*)&tdw[i2][p];
            #pragma unroll
            for (int j = 0; j < 8; ++j) xi[i2][j] = (float)v[j];
        }
        #pragma unroll
        for (int o = 0; o < 8; ++o) {
            bf16x8 ov;
            #pragma unroll
            for (int j = 0; j < 8; ++j) {
                float s = 0.f;
                #pragma unroll
                for (int i2 = 0; i2 < 8; ++i2) s += wpws[o * 8 + i2] * xi[i2][j];
                ov[j] = (__bf16)s;
            }
            *(bf16x8*)&op[(size_t)o * NPIX + p] = ov;
        }
    }
}

// ---------------------------------------------------------------------------
// Attention stage A v4b: kv via MFMA, vectorized loads, 4 pixel chunks.
// ---------------------------------------------------------------------------
__global__ __launch_bounds__(256) void attn_kv4(
    const __bf16* __restrict__ qkvb, const __bf16* __restrict__ pwb,
    const float* __restrict__ pos, const float* __restrict__ s1p,
    float* __restrict__ kvpart)
{
    __shared__ __bf16 kl[4][9][256];     // 4.5 KB / wave
    __shared__ __bf16 vl[4][9][256];
    __shared__ float red[4][16][16];
    const int chunk = blockIdx.x;        // 0..3
    const int h = blockIdx.y, b = blockIdx.z;
    const __bf16* __restrict__ src = (h < 32)
        ? qkvb + ((size_t)b * 768 + h * 24) * NPIX
        : pwb  + ((size_t)b * 768 + (h - 32) * 24) * NPIX;
    const float* __restrict__ pp = pos + (size_t)(h * 8) * NPIX;
    const float s1 = s1p[0];
    const int tid = threadIdx.x, lane = tid & 63, wid = tid >> 6;
    const int tbase = chunk * 12;
    const int nt = (chunk == 3) ? 13 : 12;   // 12*3+13 = 49 tiles = 3136 px
    const int lr = lane & 15, g = lane >> 4;

    __bf16 (*K)[256] = kl[wid];
    __bf16 (*V)[256] = vl[wid];

    {
        bf16x4 s1q, oneq;
        #pragma unroll
        for (int j = 0; j < 4; ++j) { s1q[j] = (__bf16)s1; oneq[j] = (__bf16)1.0f; }
        *(bf16x4*)&K[8][lane * 4] = s1q;
        *(bf16x4*)&V[8][lane * 4] = oneq;
    }

    f32x4 acc = {};

    for (int r = wid; r * 4 < nt; r += 4) {
        const int T = min(4, nt - r * 4);
        if (lane < T * 16) {
            const int n = (tbase + r * 4) * 64 + lane * 4;
            bf16x4 kr[8], vr[8];
            f32x4 pr[8];
            #pragma unroll
            for (int c = 0; c < 8; ++c) {
                kr[c] = *(const bf16x4*)&src[(size_t)(8 + c) * NPIX + n];
                pr[c] = *(const f32x4*)&pp[(size_t)c * NPIX + n];
                vr[c] = *(const bf16x4*)&src[(size_t)(16 + c) * NPIX + n];
            }
            float k1[8][4];
            #pragma unroll
            for (int j = 0; j < 4; ++j) {
                float u[8], s2 = 0.f;
                #pragma unroll
                for (int c = 0; c < 8; ++c) {
                    float kk = (float)kr[c][j] + pr[c][j];
                    u[c] = kk * kk;
                    s2 += u[c] * u[c];
                }
                float inv = 1.f / (sqrtf(s2) + 1e-15f);
                #pragma unroll
                for (int c = 0; c < 8; ++c) k1[c][j] = u[c] * inv;
            }
            const int px  = lane * 4;
            const int tb  = px & ~63;
            const int oct = (px >> 3) & 7;
            const int sub = px & 7;
            #pragma unroll
            for (int c = 0; c < 8; ++c) {
                bf16x4 kq;
                #pragma unroll
                for (int j = 0; j < 4; ++j) kq[j] = (__bf16)k1[c][j];
                *(bf16x4*)&K[c][tb + ((oct ^ c) << 3) + sub] = kq;
                *(bf16x4*)&V[c][tb + ((oct ^ c) << 3) + sub] = vr[c];
            }
        }
        for (int t = 0; t < T; ++t) {
            #pragma unroll
            for (int s = 0; s < 2; ++s) {
                const int off = t * 64 + (((s * 4 + g) ^ (lr & 7)) << 3);
                bf16x8 a = *(const bf16x8*)&K[lr][off];
                bf16x8 bb = *(const bf16x8*)&V[lr][off];
                acc = __builtin_amdgcn_mfma_f32_16x16x32_bf16(a, bb, acc, 0, 0, 0);
            }
        }
    }

    #pragma unroll
    for (int r = 0; r < 4; ++r) red[wid][g * 4 + r][lr] = acc[r];
    __syncthreads();
    if (tid < 81) {
        const int c = tid / 9, d = tid % 9;
        kvpart[((size_t)chunk * 512 + b * 64 + h) * 81 + tid]
            = red[0][c][d] + red[1][c][d] + red[2][c][d] + red[3][c][d];
    }
}

// ---------------------------------------------------------------------------
// Attention stage B v6: block = 64 px x 8 heads (2 heads/wave); grid
// (49,8,8)=3136 blocks; LDS 10.6 KB.  Fast tanh-GELU.  Sums 4 kv partials.
// ---------------------------------------------------------------------------
__global__ __launch_bounds__(256) void attn_out6(
    const __bf16* __restrict__ qkvb, const __bf16* __restrict__ pwb,
    const float* __restrict__ kvpart,
    const float* __restrict__ bng, const float* __restrict__ bnb,
    const float* __restrict__ bnm, const float* __restrict__ bnv,
    const float* __restrict__ s1p, __bf16* __restrict__ attb)
{
    __shared__ float kvs[8 * 81];        // 2.6 KB
    __shared__ __bf16 att[64 * 64];      // 8 KB: [px][8 heads * 8ch], swizzled
    const int b = blockIdx.z;
    const int hq0 = blockIdx.y * 8;      // head base (0,8,...,56)
    const int n0 = blockIdx.x * 64;
    const int tid = threadIdx.x, lane = tid & 63, wv_ = tid >> 6;
    const int n = n0 + lane;
    const float s1 = s1p[0];

    const int S = 512 * 81;
    for (int i = tid; i < 8 * 81; i += 256) {
        const size_t off = ((size_t)b * 64 + hq0) * 81 + i;
        kvs[i] = (kvpart[off] + kvpart[S + off])
               + (kvpart[2 * S + off] + kvpart[3 * S + off]);
    }
    __syncthreads();

    float bsc[8], bmu[8], bbe[8];
    #pragma unroll
    for (int d = 0; d < 8; ++d) {
        bsc[d] = bng[d] * rsqrtf(bnv[d] + 1e-5f);
        bmu[d] = bnm[d];
        bbe[d] = bnb[d];
    }

    #pragma unroll
    for (int hh = 0; hh < 2; ++hh) {
        const int hl = wv_ * 2 + hh;     // local head 0..7
        const int h = hq0 + hl;
        const __bf16* __restrict__ src = (h < 32)
            ? qkvb + ((size_t)b * 768 + h * 24) * NPIX
            : pwb  + ((size_t)b * 768 + (h - 32) * 24) * NPIX;
        const float* __restrict__ kvh = &kvs[hl * 81];

        // q1 = l2n(l2n(q)^2) = q^2 / ||q^2||  (exact identity)
        float q1[9], s2 = 0.f;
        #pragma unroll
        for (int c = 0; c < 8; ++c) {
            float qq = (float)src[(size_t)c * NPIX + n];
            q1[c] = qq * qq;
            s2 += q1[c] * q1[c];
        }
        float inv = 1.f / (sqrtf(s2) + 1e-15f);
        #pragma unroll
        for (int c = 0; c < 8; ++c) q1[c] *= inv;
        q1[8] = s1;

        float den = 0.f;
        #pragma unroll
        for (int c = 0; c < 9; ++c) den += q1[c] * kvh[c * 9 + 8];
        const float invd = 1.f / (den + 1e-15f);

        bf16x8 o;
        #pragma unroll
        for (int d = 0; d < 8; ++d) {
            float num = 0.f;
            #pragma unroll
            for (int c = 0; c < 9; ++c) num += q1[c] * kvh[c * 9 + d];
            float v = (float)src[(size_t)(16 + d) * NPIX + n];
            float fmv = (v - bmu[d]) * bsc[d] + bbe[d];
            o[d] = (__bf16)(num * invd + fast_gelu(fmv));
        }
        *(bf16x8*)((char*)att + lane * 128 + ((hl * 16) ^ ((lane & 7) << 4))) = o;
    }
    __syncthreads();

    #pragma unroll
    for (int p = 0; p < 2; ++p) {
        const int px = p * 32 + (tid >> 3);
        const int s = tid & 7;
        bf16x8 o = *(const bf16x8*)((const char*)att + px * 128 + ((s * 16) ^ ((px & 7) << 4)));
        *(bf16x8*)&attb[((size_t)b * NPIX + n0 + px) * 512 + hq0 * 8 + s * 8] = o;
    }
}

// ---------------------------------------------------------------------------
extern "C" void kernel_launch(void* const* d_in, const int* in_sizes, int n_in,
                              void* d_out, int out_size, void* d_ws, size_t ws_size,
                              hipStream_t stream)
{
    const float* x      = (const float*)d_in[0];
    const float* w_qkv  = (const float*)d_in[1];
    const float* w_dw   = (const float*)d_in[2];
    const float* w_pw   = (const float*)d_in[3];
    const float* pos    = (const float*)d_in[4];
    const float* s1     = (const float*)d_in[5];
    const float* bng    = (const float*)d_in[6];
    const float* bnb    = (const float*)d_in[7];
    const float* bnm    = (const float*)d_in[8];
    const float* bnv    = (const float*)d_in[9];
    const float* w_proj = (const float*)d_in[10];
    const float* pg     = (const float*)d_in[11];
    const float* pb     = (const float*)d_in[12];
    const float* pm     = (const float*)d_in[13];
    const float* pv     = (const float*)d_in[14];
    float* out = (float*)d_out;

    char* w = (char*)d_ws;
    __bf16* xT    = (__bf16*)(w);                       // 13,107,200
    __bf16* qkvb  = (__bf16*)(w + 13107200);            // 38,535,168
    __bf16* pwb   = (__bf16*)(w + 51642368);            // 38,535,168
    __bf16* attb  = (__bf16*)(w + 90177536);            // 25,690,112
    float*  kvpart= (float*) (w + 115867648);           // 4*512*81*4 = 663,552
    __bf16* wq_bf = (__bf16*)(w + 116531200);           // 393,216
    __bf16* wp_bf = (__bf16*)(w + 116924416);           // 262,144

    wcvt<<<768, 256, 0, stream>>>(w_qkv, w_proj, wq_bf, wp_bf);
    xpose_cvt<<<dim3(100, 8, 8), 256, 0, stream>>>(x, xT);

    // qkv = w_qkv(768x256) @ x  -> bf16 planar [8][768][3136]
    gemm1x1<128, 0><<<dim3(1200), 256, 0, stream>>>(
        wq_bf, xT, qkvb, 768, 256, NPIX, NPAD, 25, 6,
        nullptr, nullptr, nullptr, nullptr);

    // fused depthwise 5x5 + grouped pointwise -> pwb (no dwb round-trip)
    dwpw5<<<dim3(4, 96, 8), 256, 0, stream>>>(qkvb, w_dw, w_pw, pwb);

    attn_kv4<<<dim3(4, 64, 8), 256, 0, stream>>>(qkvb, pwb, pos, s1, kvpart);
    attn_out6<<<dim3(49, 8, 8), 256, 0, stream>>>(
        qkvb, pwb, kvpart, bng, bnb, bnm, bnv, s1, attb);

    // out = w_proj(256x512) @ attb^T + BN -> f32 planar [8][256][3136]
    gemm1x1<64, 1><<<dim3(784), 256, 0, stream>>>(
        wp_bf, attb, out, 256, 512, NPIX, NPIX, 49, 2,
        pg, pb, pm, pv);
}